// Round 6
// baseline (541.314 us; speedup 1.0000x reference)
//
#include <hip/hip_runtime.h>
#include <stdint.h>

#define BATCH 4
#define CH    256
#define NTOK  4096
#define KSEL  409          // int(0.1 * 4096)

typedef unsigned short u16;
typedef unsigned int   u32;
typedef unsigned long long u64;

typedef __attribute__((ext_vector_type(8))) _Float16 half8;
typedef __attribute__((ext_vector_type(4))) _Float16 half4;
typedef __attribute__((ext_vector_type(4))) float f32x4;
typedef __attribute__((ext_vector_type(4))) u32 u32x4;
typedef __attribute__((ext_vector_type(2))) u32 u32x2;
typedef __attribute__((ext_vector_type(4))) float fl4;

// ---------------- helpers ----------------
__device__ inline u16 h2u(_Float16 h){ u16 u; __builtin_memcpy(&u,&h,2); return u; }
// monotone float<->uint key transform (ascending)
__device__ inline float keyinv(u32 k){ u32 v=(k&0x80000000u)?(k^0x80000000u):~k; return __uint_as_float(v); }
__device__ inline void gload16(const void* g, void* l){
  __builtin_amdgcn_global_load_lds((const __attribute__((address_space(1))) u32*)g,
                                   (__attribute__((address_space(3))) u32*)l, 16, 0, 0);
}

// ---------------- phase -1: W split ----------------
// Wq/Wk/Wv [CH][CH] f32 -> W3h/W3l [3][CH][CH] fp16 hi/lo
__global__ __launch_bounds__(256) void wsplit_kernel(
    const float* __restrict__ Wq, const float* __restrict__ Wk,
    const float* __restrict__ Wv, u16* __restrict__ W3h, u16* __restrict__ W3l)
{
  const int p = blockIdx.y;
  const float* W = (p==0)? Wq : (p==1)? Wk : Wv;
  const int idx = (blockIdx.x*256 + threadIdx.x) * 4;
  fl4 v = *(const fl4*)(W + idx);
  u32x2 vh, vl;
  #pragma unroll
  for (int q=0;q<2;q++) {
    _Float16 h0=(_Float16)v[q*2], h1=(_Float16)v[q*2+1];
    _Float16 l0=(_Float16)(v[q*2]-(float)h0), l1=(_Float16)(v[q*2+1]-(float)h1);
    vh[q] = (u32)h2u(h0) | ((u32)h2u(h1)<<16);
    vl[q] = (u32)h2u(l0) | ((u32)h2u(l1)<<16);
  }
  *(u32x2*)(W3h + p*CH*CH + idx) = vh;
  *(u32x2*)(W3l + p*CH*CH + idx) = vl;
}

// ---------------- phase 0a: x transpose + split ----------------
// x [B][CH][NTOK] f32 -> xTh/xTl [B][NTOK][CH] fp16 hi/lo (64x64 LDS tiles)
__global__ __launch_bounds__(256) void xsplit_kernel(
    const float* __restrict__ x, u16* __restrict__ xTh, u16* __restrict__ xTl)
{
  __shared__ float lds[64][65];
  const int tid = threadIdx.x;
  const int n0 = blockIdx.x << 6;
  const int c0 = blockIdx.y << 6;
  const int b  = blockIdx.z;
  const float* xb = x + (size_t)b*CH*NTOK;

  #pragma unroll
  for (int i=0;i<16;i++) {
    int c_l = (tid>>6) + (i<<2);
    int n_l = tid & 63;
    lds[c_l][n_l] = xb[(size_t)(c0+c_l)*NTOK + n0 + n_l];
  }
  __syncthreads();
  u16* oh = xTh + (size_t)b*NTOK*CH;
  u16* ol = xTl + (size_t)b*NTOK*CH;
  #pragma unroll
  for (int i=0;i<16;i++) {
    int n_l = (tid>>6) + (i<<2);
    int c_l = tid & 63;
    float v = lds[c_l][n_l];
    _Float16 h = (_Float16)v;
    _Float16 l = (_Float16)(v - (float)h);
    size_t o = (size_t)(n0+n_l)*CH + c0 + c_l;
    oh[o] = h2u(h);
    ol[o] = h2u(l);
  }
}

// ---------------- phase 0b: QKV projection GEMM ----------------
// out[n][d] = sum_c xT[n][c] * W[d][c], fp32-equivalent via 3-term split-fp16 MFMA.
// Q/K stored fp16 (hi rounding only); V channel-major fp16.
__global__ __launch_bounds__(256) void proj_gemm(
    const u16* __restrict__ xTh, const u16* __restrict__ xTl,
    const u16* __restrict__ W3h, const u16* __restrict__ W3l,
    u16* __restrict__ Qh, u16* __restrict__ Kh, u16* __restrict__ Vc)
{
  __shared__ __align__(16) short lds[4*128*64];   // ah, al, bh, bl (16KB each)
  short* lds_ah = lds;
  short* lds_al = lds + 128*64;
  short* lds_bh = lds + 2*128*64;
  short* lds_bl = lds + 3*128*64;

  const int tid  = threadIdx.x;
  const int lane = tid & 63;
  const int wave = tid >> 6;
  const int wm = wave >> 1, wn = wave & 1;
  const int brow = blockIdx.x << 7;     // token tile
  const int bcol = blockIdx.y << 7;     // out-channel tile
  const int z = blockIdx.z;             // b*3 + p
  const int b = z / 3, p = z - 3*b;

  const u16* Agh = xTh + ((size_t)b*NTOK + brow)*CH;
  const u16* Agl = xTl + ((size_t)b*NTOK + brow)*CH;
  const u16* Bgh = W3h + (size_t)p*CH*CH + (size_t)bcol*CH;
  const u16* Bgl = W3l + (size_t)p*CH*CH + (size_t)bcol*CH;

  f32x4 acc[4][4];
  #pragma unroll
  for (int i=0;i<4;i++)
    #pragma unroll
    for (int j=0;j<4;j++) acc[i][j] = (f32x4)0.f;

  const int sr    = tid >> 3;
  const int sslot = tid & 7;

  for (int kt=0; kt<4; kt++) {
    #pragma unroll
    for (int c=0;c<4;c++) {
      int r  = (c<<5) + sr;
      int ss = sslot ^ (r & 7);
      size_t goff = (size_t)r*CH + (kt<<6) + (ss<<3);
      int dst = (c<<12) + (wave<<10);
      gload16(Agh + goff, (char*)lds_ah + dst);
      gload16(Agl + goff, (char*)lds_al + dst);
      gload16(Bgh + goff, (char*)lds_bh + dst);
      gload16(Bgl + goff, (char*)lds_bl + dst);
    }
    __syncthreads();
    #pragma unroll
    for (int ks=0;ks<2;ks++) {
      half8 ah[4], al[4], bh[4], bl[4];
      const int kg = lane >> 4;
      const int rl = lane & 15;
      #pragma unroll
      for (int t=0;t<4;t++) {
        int ar = (wm<<6) + (t<<4) + rl;
        int slot = (ks<<2) + kg;
        int ao = ar*64 + ((slot ^ (ar&7))<<3);
        ah[t] = *(const half8*)&lds_ah[ao];
        al[t] = *(const half8*)&lds_al[ao];
        int br = (wn<<6) + (t<<4) + rl;
        int bo = br*64 + ((slot ^ (br&7))<<3);
        bh[t] = *(const half8*)&lds_bh[bo];
        bl[t] = *(const half8*)&lds_bl[bo];
      }
      #pragma unroll
      for (int mt=0;mt<4;mt++)
        #pragma unroll
        for (int nt=0;nt<4;nt++) {
          acc[mt][nt] = __builtin_amdgcn_mfma_f32_16x16x32_f16(ah[mt], bh[nt], acc[mt][nt], 0,0,0);
          acc[mt][nt] = __builtin_amdgcn_mfma_f32_16x16x32_f16(ah[mt], bl[nt], acc[mt][nt], 0,0,0);
          acc[mt][nt] = __builtin_amdgcn_mfma_f32_16x16x32_f16(al[mt], bh[nt], acc[mt][nt], 0,0,0);
        }
    }
    __syncthreads();
  }

  const int rl = lane & 15, rg = lane >> 4;
  if (p < 2) {
    // fp16 (hi only), token-major [b][n][c]
    u16* oh = ((p==0)? Qh : Kh) + (size_t)b*NTOK*CH;
    #pragma unroll
    for (int mt=0;mt<4;mt++) {
      #pragma unroll
      for (int nt=0;nt<4;nt++) {
        int n = brow + (wm<<6) + (mt<<4) + (rg<<2);
        int c = bcol + (wn<<6) + (nt<<4) + rl;
        #pragma unroll
        for (int r=0;r<4;r++)
          oh[(size_t)(n+r)*CH + c] = h2u((_Float16)acc[mt][nt][r]);
      }
    }
  } else {
    // V: transpose in LDS -> store channel-major Vc[b][d][n] coalesced
    u16* ldsT = (u16*)lds;                 // [128][136] u16 = 34816 B
    #pragma unroll
    for (int mt=0;mt<4;mt++) {
      #pragma unroll
      for (int nt=0;nt<4;nt++) {
        int n_l = (wm<<6) + (mt<<4) + (rg<<2);
        int c_l = (wn<<6) + (nt<<4) + rl;
        half4 hv;
        #pragma unroll
        for (int r=0;r<4;r++) hv[r] = (_Float16)acc[mt][nt][r];
        *(half4*)&ldsT[c_l*136 + n_l] = hv;
      }
    }
    __syncthreads();
    u16* ov = Vc + (size_t)b*CH*NTOK + (size_t)bcol*NTOK + brow;
    #pragma unroll
    for (int i=0;i<32;i++) {
      int d_l = (tid>>6) + (i<<2);
      u32 v = *(const u32*)&ldsT[d_l*136 + (lane<<1)];
      *(u32*)(ov + (size_t)d_l*NTOK + (lane<<1)) = v;
    }
  }
}

// ---------------- phase 1: S = Q*K^T / 16 (one batch), hi-only fp16 ----------------
__global__ __launch_bounds__(256) void score_kernel(
    const u16* __restrict__ Qh, const u16* __restrict__ Kh,
    float* __restrict__ S, int b)
{
  __shared__ __align__(16) short lds_a[128*64];
  __shared__ __align__(16) short lds_b[128*64];
  const int tid  = threadIdx.x;
  const int lane = tid & 63;
  const int wave = tid >> 6;
  const int wm = wave >> 1, wn = wave & 1;
  const int brow = blockIdx.x << 7, bcol = blockIdx.y << 7;

  const u16* Ag = Qh + ((size_t)b*NTOK + brow)*CH;
  const u16* Bg = Kh + ((size_t)b*NTOK + bcol)*CH;

  f32x4 acc[4][4];
  #pragma unroll
  for (int i=0;i<4;i++)
    #pragma unroll
    for (int j=0;j<4;j++) acc[i][j] = (f32x4)0.f;

  const int sr    = tid >> 3;
  const int sslot = tid & 7;

  for (int kt=0; kt<4; kt++) {
    #pragma unroll
    for (int c=0;c<4;c++) {
      int r  = (c<<5) + sr;
      int ss = sslot ^ (r & 7);
      size_t goff = (size_t)r*CH + (kt<<6) + (ss<<3);
      int dst = (c<<12) + (wave<<10);
      gload16(Ag + goff, (char*)lds_a + dst);
      gload16(Bg + goff, (char*)lds_b + dst);
    }
    __syncthreads();
    #pragma unroll
    for (int ks=0;ks<2;ks++) {
      half8 af[4], bf[4];
      const int kg = lane >> 4;
      const int rl = lane & 15;
      #pragma unroll
      for (int t=0;t<4;t++) {
        int ar = (wm<<6) + (t<<4) + rl;
        int slot = (ks<<2) + kg;
        af[t] = *(const half8*)&lds_a[ar*64 + ((slot ^ (ar&7))<<3)];
        int br = (wn<<6) + (t<<4) + rl;
        bf[t] = *(const half8*)&lds_b[br*64 + ((slot ^ (br&7))<<3)];
      }
      #pragma unroll
      for (int mt=0;mt<4;mt++)
        #pragma unroll
        for (int nt=0;nt<4;nt++)
          acc[mt][nt] = __builtin_amdgcn_mfma_f32_16x16x32_f16(af[mt], bf[nt], acc[mt][nt], 0,0,0);
    }
    __syncthreads();
  }

  const int rl = lane & 15, rg = lane >> 4;
  #pragma unroll
  for (int mt=0;mt<4;mt++) {
    #pragma unroll
    for (int nt=0;nt<4;nt++) {
      int row = brow + (wm<<6) + (mt<<4) + (rg<<2);
      int col = bcol + (wn<<6) + (nt<<4) + rl;
      #pragma unroll
      for (int r=0;r<4;r++)
        S[(size_t)(row+r)*NTOK + col] = acc[mt][nt][r] * 0.0625f;
    }
  }
}

// ---------------- phase 2: exact per-row top-KSEL -> dense fp16 weight row ----------------
// one wave per row; 4096 keys in wave VGPRs (64/lane); exact KSEL-th-largest key via
// MSB-first 32-bit binary search with ballot+popcount counting. NO LDS, no atomics.
// Tie inclusion in index order == jax.lax.top_k.
__global__ __launch_bounds__(256) void select_kernel(
    const float* __restrict__ S, u16* __restrict__ Wd)
{
  const int lane = threadIdx.x & 63;
  const int wave = threadIdx.x >> 6;
  const int row  = (blockIdx.x << 2) + wave;
  const float* Srow = S + (size_t)row * NTOK;

  u32 key[64];
  float m = -3.4e38f;
  #pragma unroll
  for (int ch=0; ch<64; ch++) {
    float s = Srow[(ch<<6) + lane];              // element index = ch*64 + lane
    m = fmaxf(m, s);
    u32 u = __float_as_uint(s);
    key[ch] = (u & 0x80000000u) ? ~u : (u | 0x80000000u);
  }
  #pragma unroll
  for (int off=32; off; off>>=1) m = fmaxf(m, __shfl_xor(m, off, 64));

  // T = exact KSEL-th largest key: MSB-first bit descend.
  // invariant: prefix = largest value with decided bits s.t. count(key >= prefix) >= KSEL
  u32 prefix = 0;
  for (int bit=31; bit>=0; --bit) {
    u32 cand = prefix | (1u << bit);
    u32 c = 0;
    #pragma unroll
    for (int ch=0; ch<64; ch++)
      c += (u32)__popcll(__ballot(key[ch] >= cand));
    if (c >= KSEL) prefix = cand;
  }
  const u32 tkey = prefix;
  const float tf = keyinv(tkey);

  // strictly-greater count -> number of threshold ties to include (index order)
  u32 cgt = 0;
  #pragma unroll
  for (int ch=0; ch<64; ch++)
    cgt += (u32)__popcll(__ballot(key[ch] > tkey));
  const int krem = KSEL - (int)cgt;              // >= 1

  // softmax denominator over the selected set
  float z = 0.f;
  #pragma unroll
  for (int ch=0; ch<64; ch++)
    if (key[ch] > tkey) z += __expf(keyinv(key[ch]) - m);
  #pragma unroll
  for (int off=32; off; off>>=1) z += __shfl_xor(z, off, 64);
  float Z = z + (float)krem * __expf(tf - m);
  float invZ = 1.f / Z;

  // dense weight row (w for selected, 0 elsewhere), fp16
  u16* wrow = Wd + (size_t)row * NTOK;
  const u64 ltmask = (1ull << lane) - 1ull;
  int eqbase = 0;
  #pragma unroll
  for (int ch=0; ch<64; ch++) {
    u32 u = key[ch];
    bool eq = (u == tkey);
    u64 eqm = __ballot(eq);
    bool sel = (u > tkey) || (eq && (eqbase + __popcll(eqm & ltmask)) < krem);
    float w = sel ? (__expf(keyinv(u) - m) * invZ) : 0.f;
    wrow[(ch<<6) + lane] = h2u((_Float16)w);
    eqbase += __popcll(eqm);
  }
}

// ---------------- phase 3: dense PV GEMM ----------------
// out^T[c,n] = sum_k Vc[c,k] * Wd[n,k].  128(M=ch) x 64(N=tok) tiles, K=NTOK.
__global__ __launch_bounds__(256) void pv_gemm(
    const u16* __restrict__ Vc, const u16* __restrict__ Wd,
    float* __restrict__ out, int b_base, size_t wstride)
{
  __shared__ __align__(16) short lds_a[128*64];   // 16 KB
  __shared__ __align__(16) short lds_b[64*64];    //  8 KB
  const int tid  = threadIdx.x;
  const int lane = tid & 63;
  const int wave = tid >> 6;
  const int wm = wave >> 1, wn = wave & 1;
  const int b    = b_base + blockIdx.z;
  const int brow = blockIdx.x << 7;      // channel tile (0/128)
  const int bcol = blockIdx.y << 6;      // token tile (64-wide)

  const u16* Ag = Vc + (size_t)b*CH*NTOK + (size_t)brow*NTOK;
  const u16* Bg = Wd + (size_t)blockIdx.z*wstride + (size_t)bcol*NTOK;

  f32x4 acc[4][2];
  #pragma unroll
  for (int i=0;i<4;i++)
    #pragma unroll
    for (int j=0;j<2;j++) acc[i][j] = (f32x4)0.f;

  const int sr    = tid >> 3;
  const int sslot = tid & 7;

  for (int kt=0; kt<64; kt++) {
    #pragma unroll
    for (int c=0;c<4;c++) {
      int r  = (c<<5) + sr;
      int ss = sslot ^ (r & 7);
      size_t goff = (size_t)r*NTOK + (kt<<6) + (ss<<3);
      gload16(Ag + goff, (char*)lds_a + (c<<12) + (wave<<10));
    }
    #pragma unroll
    for (int c=0;c<2;c++) {
      int r  = (c<<5) + sr;
      int ss = sslot ^ (r & 7);
      size_t goff = (size_t)r*NTOK + (kt<<6) + (ss<<3);
      gload16(Bg + goff, (char*)lds_b + (c<<12) + (wave<<10));
    }
    __syncthreads();
    #pragma unroll
    for (int ks=0;ks<2;ks++) {
      half8 af[4], bf[2];
      const int kg = lane >> 4;
      const int rl = lane & 15;
      const int slot = (ks<<2) + kg;
      #pragma unroll
      for (int t=0;t<4;t++) {
        int ar = (wm<<6) + (t<<4) + rl;
        af[t] = *(const half8*)&lds_a[ar*64 + ((slot ^ (ar&7))<<3)];
      }
      #pragma unroll
      for (int t=0;t<2;t++) {
        int br = (wn<<5) + (t<<4) + rl;
        bf[t] = *(const half8*)&lds_b[br*64 + ((slot ^ (br&7))<<3)];
      }
      #pragma unroll
      for (int mt=0;mt<4;mt++)
        #pragma unroll
        for (int nt=0;nt<2;nt++)
          acc[mt][nt] = __builtin_amdgcn_mfma_f32_16x16x32_f16(af[mt], bf[nt], acc[mt][nt], 0,0,0);
    }
    __syncthreads();
  }

  float* ob = out + (size_t)b*CH*NTOK;
  const int rl = lane & 15, rg = lane >> 4;
  #pragma unroll
  for (int mt=0;mt<4;mt++) {
    #pragma unroll
    for (int nt=0;nt<2;nt++) {
      int row = brow + (wm<<6) + (mt<<4) + (rg<<2);   // channel
      int col = bcol + (wn<<5) + (nt<<4) + rl;        // token
      #pragma unroll
      for (int r=0;r<4;r++)
        ob[(size_t)(row+r)*NTOK + col] = acc[mt][nt][r];
    }
  }
}

// ---------------- launcher ----------------
extern "C" void kernel_launch(void* const* d_in, const int* in_sizes, int n_in,
                              void* d_out, int out_size, void* d_ws, size_t ws_size,
                              hipStream_t stream)
{
  (void)in_sizes; (void)n_in; (void)out_size;
  const float* x  = (const float*)d_in[0];
  const float* Wq = (const float*)d_in[1];
  const float* Wk = (const float*)d_in[2];
  const float* Wv = (const float*)d_in[3];
  float* out = (float*)d_out;

  char* ws = (char*)d_ws;
  size_t off = 0;
  const size_t plane = (size_t)BATCH*NTOK*CH*2;       // 8.4 MB fp16 plane
  const size_t NN    = (size_t)NTOK*NTOK;             // 16.8M elements
  u16* Qh = (u16*)(ws + off); off += plane;
  u16* Kh = (u16*)(ws + off); off += plane;
  u16* Vc = (u16*)(ws + off); off += plane;
  u16* W3h = (u16*)(ws + off); off += (size_t)3*CH*CH*2;
  u16* W3l = (u16*)(ws + off); off += (size_t)3*CH*CH*2;
  // xT planes live only until proj_gemm completes; Wd overlaps them afterwards.
  const size_t xt_base = off;
  u16* xTh = (u16*)(ws + xt_base);
  u16* xTl = (u16*)(ws + xt_base + plane);
  const size_t fullW_need = xt_base + (size_t)BATCH*NN*2 + NN*4;   // ~227 MiB
  const bool fullW = ws_size >= fullW_need;
  u16* Wd = (u16*)(ws + xt_base);
  float* S = (float*)(ws + xt_base + (fullW ? (size_t)BATCH*NN*2 : NN*2));

  wsplit_kernel<<<dim3(64,3), 256, 0, stream>>>(Wq, Wk, Wv, W3h, W3l);
  xsplit_kernel<<<dim3(64,4,4), 256, 0, stream>>>(x, xTh, xTl);
  proj_gemm<<<dim3(32,2,12), 256, 0, stream>>>(xTh, xTl, W3h, W3l, Qh, Kh, Vc);

  if (fullW) {
    for (int b=0; b<BATCH; b++) {
      score_kernel<<<dim3(32,32), 256, 0, stream>>>(Qh, Kh, S, b);
      select_kernel<<<1024, 256, 0, stream>>>(S, Wd + (size_t)b*NN);
    }
    pv_gemm<<<dim3(2,64,4), 256, 0, stream>>>(Vc, Wd, out, 0, NN);
  } else {
    for (int b=0; b<BATCH; b++) {
      score_kernel<<<dim3(32,32), 256, 0, stream>>>(Qh, Kh, S, b);
      select_kernel<<<1024, 256, 0, stream>>>(S, Wd);
      pv_gemm<<<dim3(2,64,1), 256, 0, stream>>>(Vc, Wd, out, b, 0);
    }
  }
}